// Round 4
// baseline (186.927 us; speedup 1.0000x reference)
//
#include <hip/hip_runtime.h>
#include <stdint.h>

typedef __bf16 bf16_t;
typedef bf16_t bf16x8 __attribute__((ext_vector_type(8)));
typedef bf16_t bf16x2v __attribute__((ext_vector_type(2)));
typedef float f32x4 __attribute__((ext_vector_type(4)));
typedef float f32x16 __attribute__((ext_vector_type(16)));
typedef uint32_t u32x2 __attribute__((ext_vector_type(2)));
typedef uint32_t u32x4 __attribute__((ext_vector_type(4)));

#define BATCH 2
#define SEQ 2048
#define CDIM 1024
#define NH 16
#define HD 64

// softmax scale folded into Q at gemm1: (1/sqrt(64)) * log2(e)
#define QSCALE 0.18033688011f

__device__ __forceinline__ uint16_t f32_bf16(float f) {
    __bf16 h = (__bf16)f;   // RNE; ISel picks v_cvt_*_bf16 on gfx950
    return __builtin_bit_cast(uint16_t, h);
}

// pack two f32 -> u32 of 2xbf16 (lo=a, hi=b); ISel can fuse to v_cvt_pk_bf16_f32
__device__ __forceinline__ uint32_t pack_bf16(float a, float b) {
    bf16x2v t;
    t.x = (__bf16)a;
    t.y = (__bf16)b;
    return __builtin_bit_cast(uint32_t, t);
}

__device__ __forceinline__ bf16x8 ld8(const uint16_t* p) {
    return *reinterpret_cast<const bf16x8*>(p);
}

// v_permlane32_swap_b32: a' = {a.lo32lanes, b.lo32lanes}, b' = {a.hi32lanes, b.hi32lanes}
__device__ __forceinline__ void swap32(uint32_t& a, uint32_t& b) {
#if __has_builtin(__builtin_amdgcn_permlane32_swap)
    u32x2 r = __builtin_amdgcn_permlane32_swap(a, b, false, false);
    a = r.x;
    b = r.y;
#else
    asm("v_permlane32_swap_b32 %0, %1" : "+v"(a), "+v"(b));
#endif
}

// async global->LDS, 16B per lane; LDS dest = wave-uniform base + lane*16
__device__ __forceinline__ void gld16(const uint16_t* g, uint16_t* l) {
    __builtin_amdgcn_global_load_lds(
        (__attribute__((address_space(1))) void*)(g),
        (__attribute__((address_space(3))) void*)(l), 16, 0, 0);
}

// wave-local LDS fence: order own ds_writes before own ds_reads (wave-private tiles)
#define LDS_FENCE() asm volatile("s_waitcnt lgkmcnt(0)" ::: "memory")

// -------- prep: x cast (blocks 0..4095), Wqkv^T (next 3072), Wout^T (next 1024) ----
__global__ __launch_bounds__(256) void prep_kernel(
        const float* __restrict__ x, uint16_t* __restrict__ x_bf,
        const float* __restrict__ Wqkv, uint16_t* __restrict__ wqkvT,
        const float* __restrict__ Wout, uint16_t* __restrict__ woutT) {
    const int bid = blockIdx.x, tid = threadIdx.x;
    if (bid < 4096) {
        int i = (bid * 256 + tid) * 4;
        float4 v = *(const float4*)(x + i);
        ushort4 o;
        o.x = f32_bf16(v.x);
        o.y = f32_bf16(v.y);
        o.z = f32_bf16(v.z);
        o.w = f32_bf16(v.w);
        *(ushort4*)(x_bf + i) = o;
        return;
    }
    __shared__ float tile[32][33];
    const float* in;
    uint16_t* outp;
    int idx, Cc, ncx;
    if (bid < 4096 + 3072) { idx = bid - 4096; in = Wqkv; outp = wqkvT; Cc = 3072; ncx = 96; }
    else                   { idx = bid - 7168; in = Wout; outp = woutT; Cc = 1024; ncx = 32; }
    const int R = 1024;
    int bx = idx % ncx, by = idx / ncx;
    int c0 = bx * 32, r0 = by * 32;
    int tx = tid & 31, ty = tid >> 5;   // 32 x 8
#pragma unroll
    for (int i = 0; i < 4; i++)
        tile[ty + i * 8][tx] = in[(size_t)(r0 + ty + i * 8) * Cc + c0 + tx];
    __syncthreads();
    // vectorized store phase: thread -> (rr = output row within tile, seg of 4 r's)
    const int rr = tid >> 3, seg = tid & 7;
    ushort4 o;
    o.x = f32_bf16(tile[seg * 4 + 0][rr]);
    o.y = f32_bf16(tile[seg * 4 + 1][rr]);
    o.z = f32_bf16(tile[seg * 4 + 2][rr]);
    o.w = f32_bf16(tile[seg * 4 + 3][rr]);
    *(ushort4*)(outp + (size_t)(c0 + rr) * R + r0 + seg * 4) = o;
}

// ------------- templated MFMA GEMM, A[M,K] bf16, Bt[N,K] bf16, dbuf K-loop -------
// MODE 0 (BM=BN=128): qkv epilogue via per-wave LDS transpose (Ts overlaid on
//   the staging buffers): q (xQSCALE), k -> [B,H,N,d]; v -> vt [B,H,d,N] PLAIN.
//   R3: epilogue global stores re-mapped so each store instruction covers
//   8 rows x 128B contiguous (was: 64-line scatter, 8-16x request amplification).
// MODE 1: bias + f32 row-major out[M, CDIM].
template <int BM, int BN, int MODE>
__global__ __launch_bounds__(256) void gemm_t(
        const uint16_t* __restrict__ A, const uint16_t* __restrict__ Bt, int K,
        const float* __restrict__ bias,
        uint16_t* __restrict__ qw, uint16_t* __restrict__ kw, uint16_t* __restrict__ vt,
        float* __restrict__ out) {
    constexpr int WT_M = BM / 2, WT_N = BN / 2;
    constexpr int MI = WT_M / 16, NJ = WT_N / 16;
    constexpr int ASEG_W = BM / 64, BSEG_W = BN / 64;   // 1KB segs per wave
    constexpr int AB = 2 * BM * 32 + 2 * BN * 32;
    constexpr int TS = (MODE == 0) ? 4 * 64 * 68 : 0;
    constexpr int SM = AB > TS ? AB : TS;
    __shared__ uint16_t smem[SM];
    uint16_t* As = smem;                 // [2][BM*32]
    uint16_t* Bs = smem + 2 * BM * 32;   // [2][BN*32]

    const int m0 = blockIdx.y * BM, n0 = blockIdx.x * BN;
    const int tid = threadIdx.x;
    const int w = tid >> 6, lane = tid & 63;
    const int quad = lane >> 4, l16 = lane & 15;
    const int wm = (w >> 1) * WT_M, wn = (w & 1) * WT_N;

    const int srow = lane >> 2;                    // row within 16-row seg
    const int schunk = (lane & 3) ^ (srow & 3);    // XOR-swizzled source chunk

    const uint16_t* aP[ASEG_W];
    const uint16_t* bP[BSEG_W];
    int aL[ASEG_W], bL[BSEG_W];
#pragma unroll
    for (int s = 0; s < ASEG_W; s++) {
        int seg = w * ASEG_W + s;
        aP[s] = A + (size_t)(m0 + seg * 16 + srow) * K + schunk * 8;
        aL[s] = seg * 512;
    }
#pragma unroll
    for (int s = 0; s < BSEG_W; s++) {
        int seg = w * BSEG_W + s;
        bP[s] = Bt + (size_t)(n0 + seg * 16 + srow) * K + schunk * 8;
        bL[s] = seg * 512;
    }

    auto stage = [&](int buf, int k0) {
#pragma unroll
        for (int s = 0; s < ASEG_W; s++) gld16(aP[s] + k0, As + buf * BM * 32 + aL[s]);
#pragma unroll
        for (int s = 0; s < BSEG_W; s++) gld16(bP[s] + k0, Bs + buf * BN * 32 + bL[s]);
    };

    const int cslot = (quad ^ (l16 & 3)) * 8;
    f32x4 acc[MI][NJ] = {};

    stage(0, 0);
    const int iters = K / 32;
    for (int it = 0; it < iters; ++it) {
        __syncthreads();     // drains tile-it DMA; prev buffer's readers all done
        if (it + 1 < iters) stage((it + 1) & 1, (it + 1) * 32);
        const uint16_t* A_ = As + (it & 1) * BM * 32;
        const uint16_t* B_ = Bs + (it & 1) * BN * 32;
        bf16x8 af[MI], bfr[NJ];
#pragma unroll
        for (int i = 0; i < MI; i++) af[i] = ld8(&A_[(wm + i * 16 + l16) * 32 + cslot]);
#pragma unroll
        for (int j = 0; j < NJ; j++) bfr[j] = ld8(&B_[(wn + j * 16 + l16) * 32 + cslot]);
#pragma unroll
        for (int i = 0; i < MI; i++)
#pragma unroll
            for (int j = 0; j < NJ; j++)
                acc[i][j] = __builtin_amdgcn_mfma_f32_16x16x32_bf16(af[i], bfr[j], acc[i][j], 0, 0, 0);
    }

    const int nbase = n0 + wn;
    float bj[NJ];
#pragma unroll
    for (int j = 0; j < NJ; j++) bj[j] = bias[nbase + j * 16 + l16];

    if constexpr (MODE == 1) {
#pragma unroll
        for (int j = 0; j < NJ; j++) {
#pragma unroll
            for (int i = 0; i < MI; i++)
#pragma unroll
                for (int r = 0; r < 4; r++) {
                    int m = m0 + wm + i * 16 + quad * 4 + r;
                    out[(size_t)m * CDIM + nbase + j * 16 + l16] = acc[i][j][r] + bj[j];
                }
        }
    } else {
        // ---- qkv epilogue; Ts overlays the staging buffers (loop is done) ----
        __syncthreads();                 // all waves done with As/Bs ds_reads
        uint16_t* T = smem + w * 64 * 68;
        const int gmb = m0 + wm;         // 64-aligned block of m (= ns) rows
        const int b = gmb >> 11, ns0 = gmb & 2047;
        const int lrow = lane >> 3, lch = lane & 7;   // store remap: 8 rows x 8 chunks

        if (nbase < 2048) {
            // q/k wave: T[m][n] m-major (stride 68); q gets QSCALE folded in
            const int which = nbase >> 10, h = (nbase & 1023) >> 6;
            const float sc = (which == 0) ? QSCALE : 1.0f;
#pragma unroll
            for (int i = 0; i < 4; i++)
#pragma unroll
                for (int j = 0; j < 4; j++)
#pragma unroll
                    for (int r = 0; r < 4; r++)
                        T[(i * 16 + quad * 4 + r) * 68 + j * 16 + l16] =
                            f32_bf16((acc[i][j][r] + bj[j]) * sc);
            LDS_FENCE();
            uint16_t* dst = ((which == 0) ? qw : kw) +
                            (((size_t)b * NH + h) * SEQ + ns0) * HD;
            // coalesced: per g, lanes cover rows g*8..g*8+7 fully (8x128B contig)
#pragma unroll
            for (int g = 0; g < 8; g++) {
                int r = g * 8 + lrow;
                bf16x8 v = ld8(&T[r * 68 + lch * 8]);
                *(bf16x8*)(dst + (size_t)r * HD + lch * 8) = v;
            }
        } else {
            // v wave: T[n(dd)][m(ns)] n-major; PLAIN [B,H,d,N] coalesced stores
#pragma unroll
            for (int i = 0; i < 4; i++)
#pragma unroll
                for (int j = 0; j < 4; j++) {
                    u32x2 pr;
                    pr.x = pack_bf16(acc[i][j][0] + bj[j], acc[i][j][1] + bj[j]);
                    pr.y = pack_bf16(acc[i][j][2] + bj[j], acc[i][j][3] + bj[j]);
                    *(u32x2*)&T[(j * 16 + l16) * 68 + i * 16 + quad * 4] = pr;
                }
            LDS_FENCE();
            const int h = (nbase - 2048) >> 6;
            uint16_t* dstb = vt + ((size_t)b * NH + h) * HD * SEQ + ns0;
            // per g: d-rows g*8..g*8+7, each 64 kv elems (128B) fully covered
#pragma unroll
            for (int g = 0; g < 8; g++) {
                int dr = g * 8 + lrow;
                bf16x8 v2 = ld8(&T[dr * 68 + lch * 8]);
                *(bf16x8*)(dstb + (size_t)dr * SEQ + lch * 8) = v2;
            }
        }
    }
}

// ---------------- flash attention: KV-tile 128, 32 q-rows per wave, 32x32 MFMA ----
// R3 schedule (resubmit — R3 bench was an infra failure, kernel never measured):
//   - Next tile's kvb=0 K-frags prefetched FROM GLOBAL into registers at kvb==2
//     (L2-hot: the DMA streamed those bytes one tile earlier). QK for the next
//     tile's S[0] runs in phase kvb==3 — no post-barrier serial prologue; the
//     global-register path also sidesteps cross-wave LDS DMA visibility.
//   - T5: s_setprio(1) around each phase's QK+PV MFMA cluster.
// Layouts (verified R1/R2): S^T = mfma_32x32x16(K-frag, Q-frag); C: col=q=lane&31,
// row=kv=(reg&3)+8*(reg>>2)+4*(lane>>5). p=exp2(S) -> cvt_pk pairs; 2x
// permlane32_swap build each 16-kv B-frag; PV = mfma(V-frag, P-frag); l on VALU.
__global__ __launch_bounds__(256) void attn_kernel(
        const uint16_t* __restrict__ qg, const uint16_t* __restrict__ kg,
        const uint16_t* __restrict__ vt, uint16_t* __restrict__ og) {
    __shared__ uint16_t Ks[2][128 * 64];  // [kv][d], 8x16B chunks/row, chunk ^= kv&7
    __shared__ uint16_t Vs[2][64 * 128];  // [d][kv], 16x16B chunks/row, chunk ^= d&15

    const int bh = blockIdx.x;         // 0..31  — XCD-affine (linear id % 8 = bh % 8)
    const int qt = blockIdx.y;         // 0..15
    const int tid = threadIdx.x;
    const int w = tid >> 6, lane = tid & 63;
    const int l32 = lane & 31, hi = lane >> 5;
    const int qrow0 = qt * 128 + w * 32;
    const size_t base = (size_t)bh * SEQ * HD;

    // Q B-frags: col = q = l32, k = d = s*16 + hi*8 + idx (held all kernel)
    bf16x8 qf[4];
#pragma unroll
    for (int s = 0; s < 4; s++)
        qf[s] = ld8(qg + base + (size_t)(qrow0 + l32) * HD + s * 16 + hi * 8);

    // K staging: 16 segs of 8 kv-rows (1KB); wave w stages segs 4w..4w+3.
    const int krow = lane >> 3;
    const int kch = (lane & 7) ^ krow;
    // V staging: 16 segs of 4 d-rows x 128 kv (1KB); wave w stages segs 4w..4w+3.
    const int vrow = lane >> 4;
    const uint16_t* ksrc[4];
    const uint16_t* vsrc[4];
#pragma unroll
    for (int s = 0; s < 4; s++) {
        int seg = w * 4 + s;
        ksrc[s] = kg + base + (size_t)(seg * 8 + krow) * HD + kch * 8;
        int vd = seg * 4 + vrow;                       // d row
        int vch = (lane & 15) ^ (vd & 15);             // source chunk (4-bit xor)
        vsrc[s] = vt + base + (size_t)vd * SEQ + vch * 8;
    }

    f32x16 o_acc[2] = {};   // [mf]: d = mf*32 + (reg&3)+8*(reg>>2)+4*hi, col q=l32
    float l_red = 0.0f;     // per-lane partial: sum_kv(this lane's 16 kv rows) p

    auto stage = [&](int buf) {
        // K first: consumed first after the next barrier
#pragma unroll
        for (int s = 0; s < 4; s++) {
            int seg = w * 4 + s;
            gld16(ksrc[s], &Ks[buf][seg * 512]);
            ksrc[s] += 128 * HD;
        }
#pragma unroll
        for (int s = 0; s < 4; s++) {
            int seg = w * 4 + s;
            gld16(vsrc[s], &Vs[buf][seg * 512]);
            vsrc[s] += 128;
        }
    };

    // prologue: stage tile 0 into buffer 0 (DMA), then compute tile-0 S[0]
    // directly from GLOBAL K (no LDS/barrier dependency).
    stage(0);

    // hoisted read offsets (constant across tiles)
    const int kxe = l32 & 7;    // K read xor: (row&7), row = kvb*32+l32
    const int vxe = l32 & 15;   // V read xor: (row&15), row = mf*32+l32
    const int krowb = l32 * 64;
    const int vrowb = l32 * 128;
    int kco[4];
#pragma unroll
    for (int s = 0; s < 4; s++) kco[s] = ((2 * s + hi) ^ kxe) * 8;
    int vco[4][2];
#pragma unroll
    for (int kvb = 0; kvb < 4; kvb++)
#pragma unroll
        for (int cp = 0; cp < 2; cp++)
            vco[kvb][cp] = ((kvb * 4 + cp * 2 + hi) ^ vxe) * 8;

    const f32x16 fzero = {};
    // per-lane global K-frag base: row = l32 (+tile*128), chunk hi*8 + s*16
    const uint16_t* kg_pref = kg + base + (size_t)l32 * HD + hi * 8;

    f32x16 S[2];
    {
        bf16x8 k0[4];
#pragma unroll
        for (int s = 0; s < 4; s++) k0[s] = ld8(kg_pref + s * 16);
        S[0] = fzero;
        __builtin_amdgcn_s_setprio(1);
#pragma unroll
        for (int s = 0; s < 4; s++)
            S[0] = __builtin_amdgcn_mfma_f32_32x32x16_bf16(k0[s], qf[s], S[0], 0, 0, 0);
        __builtin_amdgcn_s_setprio(0);
    }

    const int NT = SEQ / 128;            // 16 tiles
    for (int it = 0; it < NT; ++it) {
        __syncthreads();   // tile-it K/V resident; prev buffer free for overwrite
        if (it + 1 < NT) stage((it + 1) & 1);
        const uint16_t* K_ = Ks[it & 1];
        const uint16_t* V_ = Vs[it & 1];
        bf16x8 kf3[4];     // next tile's kvb=0 K-frags (global, loaded at kvb==2)

#pragma unroll
        for (int kvb = 0; kvb < 4; kvb++) {
            const int cur = kvb & 1, nxt = cur ^ 1;

            // 1) K-frag prefetch feeding the next S (LDS for kvb<3)
            bf16x8 kf[4];
            if (kvb < 3) {
#pragma unroll
                for (int s = 0; s < 4; s++)
                    kf[s] = ld8(K_ + (kvb + 1) * 2048 + krowb + kco[s]);
            }
            // global prefetch of next tile's kvb=0 frags, one phase of slack
            if (kvb == 2 && it + 1 < NT) {
                const uint16_t* kgp = kg_pref + (size_t)(it + 1) * (128 * HD);
#pragma unroll
                for (int s = 0; s < 4; s++) kf3[s] = ld8(kgp + s * 16);
            }

            // 2) this-kvb V-frag reads (consumed at phase end)
            bf16x8 vf[2][2];
#pragma unroll
            for (int cp = 0; cp < 2; cp++)
#pragma unroll
                for (int mf = 0; mf < 2; mf++)
                    vf[cp][mf] = ld8(V_ + vrowb + mf * 4096 + vco[kvb][cp]);

            // 3) softmax numerators p = exp2(S[cur]); l on the VALU add tree
            float p[16];
#pragma unroll
            for (int i = 0; i < 16; i++) p[i] = __builtin_amdgcn_exp2f(S[cur][i]);
            {
                float s0 = (p[0] + p[1]) + (p[2] + p[3]);
                float s1 = (p[4] + p[5]) + (p[6] + p[7]);
                float s2 = (p[8] + p[9]) + (p[10] + p[11]);
                float s3 = (p[12] + p[13]) + (p[14] + p[15]);
                l_red += (s0 + s1) + (s2 + s3);
            }
            uint32_t pk0[4], pk1[4];
#pragma unroll
            for (int c = 0; c < 4; c++) {
                pk0[c] = pack_bf16(p[4 * c + 0], p[4 * c + 1]);
                pk1[c] = pack_bf16(p[4 * c + 2], p[4 * c + 3]);
            }

            // 4) next-S QK MFMAs (kvb<3: from LDS; kvb==3: next tile from regs)
            __builtin_amdgcn_s_setprio(1);
            if (kvb < 3) {
                S[nxt] = fzero;
#pragma unroll
                for (int s = 0; s < 4; s++)
                    S[nxt] = __builtin_amdgcn_mfma_f32_32x32x16_bf16(kf[s], qf[s], S[nxt], 0, 0, 0);
            } else if (it + 1 < NT) {
                S[nxt] = fzero;
#pragma unroll
                for (int s = 0; s < 4; s++)
                    S[nxt] = __builtin_amdgcn_mfma_f32_32x32x16_bf16(kf3[s], qf[s], S[nxt], 0, 0, 0);
            }

            // 5) PV for kvb
#pragma unroll
            for (int cp = 0; cp < 2; cp++) {
                uint32_t b0 = pk0[2 * cp], b2 = pk0[2 * cp + 1];
                uint32_t b1 = pk1[2 * cp], b3 = pk1[2 * cp + 1];
                swap32(b0, b2);   // -> word#0 (k idx 0,1), word#2 (k idx 4,5)
                swap32(b1, b3);   // -> word#1 (k idx 2,3), word#3 (k idx 6,7)
                u32x4 t;
                t.x = b0; t.y = b1; t.z = b2; t.w = b3;
                bf16x8 pb = __builtin_bit_cast(bf16x8, t);
#pragma unroll
                for (int mf = 0; mf < 2; mf++)
                    o_acc[mf] = __builtin_amdgcn_mfma_f32_32x32x16_bf16(vf[cp][mf], pb, o_acc[mf], 0, 0, 0);
            }
            __builtin_amdgcn_s_setprio(0);
        }
    }

    // ---- epilogue: cross-half l reduction (1 permlane swap + add), O write ----
    uint32_t la = __builtin_bit_cast(uint32_t, l_red), lb = la;
    swap32(la, lb);
    const float l_tot = __builtin_bit_cast(float, la) + __builtin_bit_cast(float, lb);
    const float inv = __builtin_amdgcn_rcpf(l_tot);

    const int b = bh >> 4, h = bh & 15;
    const int ns = qrow0 + l32;
    uint16_t* orow = og + (((size_t)b * SEQ + ns) * NH + h) * HD;
#pragma unroll
    for (int mf = 0; mf < 2; mf++)
#pragma unroll
        for (int c = 0; c < 4; c++) {
            u32x2 pr;
            pr.x = pack_bf16(o_acc[mf][4 * c + 0] * inv, o_acc[mf][4 * c + 1] * inv);
            pr.y = pack_bf16(o_acc[mf][4 * c + 2] * inv, o_acc[mf][4 * c + 3] * inv);
            *(u32x2*)(orow + mf * 32 + c * 8 + hi * 4) = pr;
        }
}

extern "C" void kernel_launch(void* const* d_in, const int* in_sizes, int n_in,
                              void* d_out, int out_size, void* d_ws, size_t ws_size,
                              hipStream_t stream) {
    const float* x = (const float*)d_in[0];
    const float* Wqkv = (const float*)d_in[1];
    const float* bqkv = (const float*)d_in[2];
    const float* Wout = (const float*)d_in[3];
    const float* bout = (const float*)d_in[4];
    float* out = (float*)d_out;

    uint16_t* ws = (uint16_t*)d_ws;
    uint16_t* x_bf  = ws;                      // 4096*1024
    uint16_t* wqkvT = x_bf + 4194304;          // 3072*1024
    uint16_t* woutT = wqkvT + 3145728;         // 1024*1024
    uint16_t* qw    = woutT + 1048576;         // [B,H,N,d], pre-scaled by QSCALE
    uint16_t* kw    = qw + 4194304;            // [B,H,N,d]
    uint16_t* vtw   = kw + 4194304;            // [B,H,d,N] plain
    uint16_t* attn  = vtw + 4194304;           // [B,N,H,d]

    // cast x + transpose both weight matrices, one launch
    prep_kernel<<<8192, 256, 0, stream>>>(x, x_bf, Wqkv, wqkvT, Wout, woutT);

    // qkv = x @ Wqkv + b ; q (scaled) / k -> [B,H,N,d]; v -> [B,H,d,N] plain
    gemm_t<128, 128, 0><<<dim3(24, 32), 256, 0, stream>>>(
        x_bf, wqkvT, 1024, bqkv, qw, kw, vtw, nullptr);

    // flash attention -> attn [B,N,H,d] bf16   (grid.x = bh for XCD affinity)
    attn_kernel<<<dim3(32, 16), 256, 0, stream>>>(qw, kw, vtw, attn);

    // out = attn @ Wout + b_out (f32); 64x128 tiles -> 512 blocks (2/CU)
    gemm_t<64, 128, 1><<<dim3(8, 64), 256, 0, stream>>>(
        attn, woutT, 1024, bout, nullptr, nullptr, nullptr, out);
}

// Round 5
// 178.489 us; speedup vs baseline: 1.0473x; 1.0473x over previous
//
#include <hip/hip_runtime.h>
#include <stdint.h>

typedef __bf16 bf16_t;
typedef bf16_t bf16x8 __attribute__((ext_vector_type(8)));
typedef bf16_t bf16x2v __attribute__((ext_vector_type(2)));
typedef float f32x4 __attribute__((ext_vector_type(4)));
typedef float f32x16 __attribute__((ext_vector_type(16)));
typedef uint32_t u32x2 __attribute__((ext_vector_type(2)));
typedef uint32_t u32x4 __attribute__((ext_vector_type(4)));

#define BATCH 2
#define SEQ 2048
#define CDIM 1024
#define NH 16
#define HD 64

// softmax scale folded into Q at gemm1: (1/sqrt(64)) * log2(e)
#define QSCALE 0.18033688011f

__device__ __forceinline__ uint16_t f32_bf16(float f) {
    __bf16 h = (__bf16)f;   // RNE; ISel picks v_cvt_*_bf16 on gfx950
    return __builtin_bit_cast(uint16_t, h);
}

// pack two f32 -> u32 of 2xbf16 (lo=a, hi=b); ISel can fuse to v_cvt_pk_bf16_f32
__device__ __forceinline__ uint32_t pack_bf16(float a, float b) {
    bf16x2v t;
    t.x = (__bf16)a;
    t.y = (__bf16)b;
    return __builtin_bit_cast(uint32_t, t);
}

__device__ __forceinline__ bf16x8 ld8(const uint16_t* p) {
    return *reinterpret_cast<const bf16x8*>(p);
}

// v_permlane32_swap_b32: a' = {a.lo32lanes, b.lo32lanes}, b' = {a.hi32lanes, b.hi32lanes}
__device__ __forceinline__ void swap32(uint32_t& a, uint32_t& b) {
#if __has_builtin(__builtin_amdgcn_permlane32_swap)
    u32x2 r = __builtin_amdgcn_permlane32_swap(a, b, false, false);
    a = r.x;
    b = r.y;
#else
    asm("v_permlane32_swap_b32 %0, %1" : "+v"(a), "+v"(b));
#endif
}

// async global->LDS, 16B per lane; LDS dest = wave-uniform base + lane*16
__device__ __forceinline__ void gld16(const uint16_t* g, uint16_t* l) {
    __builtin_amdgcn_global_load_lds(
        (__attribute__((address_space(1))) void*)(g),
        (__attribute__((address_space(3))) void*)(l), 16, 0, 0);
}

// wave-local LDS fence: order own ds_writes before own ds_reads (wave-private tiles)
#define LDS_FENCE() asm volatile("s_waitcnt lgkmcnt(0)" ::: "memory")
// drain own K-DMAs (4 oldest of the 8 outstanding K+V gld16s), leave V in flight
#define WAIT_K_DMA() do { \
    asm volatile("s_waitcnt vmcnt(4)" ::: "memory"); \
    __builtin_amdgcn_sched_barrier(0); \
} while (0)

// -------- prep: x cast (blocks 0..4095), Wqkv^T (next 3072), Wout^T (next 1024) ----
__global__ __launch_bounds__(256) void prep_kernel(
        const float* __restrict__ x, uint16_t* __restrict__ x_bf,
        const float* __restrict__ Wqkv, uint16_t* __restrict__ wqkvT,
        const float* __restrict__ Wout, uint16_t* __restrict__ woutT) {
    const int bid = blockIdx.x, tid = threadIdx.x;
    if (bid < 4096) {
        int i = (bid * 256 + tid) * 4;
        float4 v = *(const float4*)(x + i);
        ushort4 o;
        o.x = f32_bf16(v.x);
        o.y = f32_bf16(v.y);
        o.z = f32_bf16(v.z);
        o.w = f32_bf16(v.w);
        *(ushort4*)(x_bf + i) = o;
        return;
    }
    __shared__ float tile[32][33];
    const float* in;
    uint16_t* outp;
    int idx, Cc, ncx;
    if (bid < 4096 + 3072) { idx = bid - 4096; in = Wqkv; outp = wqkvT; Cc = 3072; ncx = 96; }
    else                   { idx = bid - 7168; in = Wout; outp = woutT; Cc = 1024; ncx = 32; }
    const int R = 1024;
    int bx = idx % ncx, by = idx / ncx;
    int c0 = bx * 32, r0 = by * 32;
    int tx = tid & 31, ty = tid >> 5;   // 32 x 8
#pragma unroll
    for (int i = 0; i < 4; i++)
        tile[ty + i * 8][tx] = in[(size_t)(r0 + ty + i * 8) * Cc + c0 + tx];
    __syncthreads();
    // vectorized store phase: thread -> (rr = output row within tile, seg of 4 r's)
    const int rr = tid >> 3, seg = tid & 7;
    ushort4 o;
    o.x = f32_bf16(tile[seg * 4 + 0][rr]);
    o.y = f32_bf16(tile[seg * 4 + 1][rr]);
    o.z = f32_bf16(tile[seg * 4 + 2][rr]);
    o.w = f32_bf16(tile[seg * 4 + 3][rr]);
    *(ushort4*)(outp + (size_t)(c0 + rr) * R + r0 + seg * 4) = o;
}

// ------------- templated MFMA GEMM, A[M,K] bf16, Bt[N,K] bf16, dbuf K-loop -------
// MODE 0 (BM=BN=128): qkv epilogue via per-wave LDS transpose (Ts overlaid on
//   the staging buffers): q (xQSCALE), k -> [B,H,N,d]; v -> vt [B,H,d,N] PLAIN.
//   Epilogue stores coalesced: each store instruction covers 8 rows x 128B.
// MODE 1: bias + f32 row-major out[M, CDIM].
template <int BM, int BN, int MODE>
__global__ __launch_bounds__(256) void gemm_t(
        const uint16_t* __restrict__ A, const uint16_t* __restrict__ Bt, int K,
        const float* __restrict__ bias,
        uint16_t* __restrict__ qw, uint16_t* __restrict__ kw, uint16_t* __restrict__ vt,
        float* __restrict__ out) {
    constexpr int WT_M = BM / 2, WT_N = BN / 2;
    constexpr int MI = WT_M / 16, NJ = WT_N / 16;
    constexpr int ASEG_W = BM / 64, BSEG_W = BN / 64;   // 1KB segs per wave
    constexpr int AB = 2 * BM * 32 + 2 * BN * 32;
    constexpr int TS = (MODE == 0) ? 4 * 64 * 68 : 0;
    constexpr int SM = AB > TS ? AB : TS;
    __shared__ uint16_t smem[SM];
    uint16_t* As = smem;                 // [2][BM*32]
    uint16_t* Bs = smem + 2 * BM * 32;   // [2][BN*32]

    const int m0 = blockIdx.y * BM, n0 = blockIdx.x * BN;
    const int tid = threadIdx.x;
    const int w = tid >> 6, lane = tid & 63;
    const int quad = lane >> 4, l16 = lane & 15;
    const int wm = (w >> 1) * WT_M, wn = (w & 1) * WT_N;

    const int srow = lane >> 2;                    // row within 16-row seg
    const int schunk = (lane & 3) ^ (srow & 3);    // XOR-swizzled source chunk

    const uint16_t* aP[ASEG_W];
    const uint16_t* bP[BSEG_W];
    int aL[ASEG_W], bL[BSEG_W];
#pragma unroll
    for (int s = 0; s < ASEG_W; s++) {
        int seg = w * ASEG_W + s;
        aP[s] = A + (size_t)(m0 + seg * 16 + srow) * K + schunk * 8;
        aL[s] = seg * 512;
    }
#pragma unroll
    for (int s = 0; s < BSEG_W; s++) {
        int seg = w * BSEG_W + s;
        bP[s] = Bt + (size_t)(n0 + seg * 16 + srow) * K + schunk * 8;
        bL[s] = seg * 512;
    }

    auto stage = [&](int buf, int k0) {
#pragma unroll
        for (int s = 0; s < ASEG_W; s++) gld16(aP[s] + k0, As + buf * BM * 32 + aL[s]);
#pragma unroll
        for (int s = 0; s < BSEG_W; s++) gld16(bP[s] + k0, Bs + buf * BN * 32 + bL[s]);
    };

    const int cslot = (quad ^ (l16 & 3)) * 8;
    f32x4 acc[MI][NJ] = {};

    stage(0, 0);
    const int iters = K / 32;
    for (int it = 0; it < iters; ++it) {
        __syncthreads();     // drains tile-it DMA; prev buffer's readers all done
        if (it + 1 < iters) stage((it + 1) & 1, (it + 1) * 32);
        const uint16_t* A_ = As + (it & 1) * BM * 32;
        const uint16_t* B_ = Bs + (it & 1) * BN * 32;
        bf16x8 af[MI], bfr[NJ];
#pragma unroll
        for (int i = 0; i < MI; i++) af[i] = ld8(&A_[(wm + i * 16 + l16) * 32 + cslot]);
#pragma unroll
        for (int j = 0; j < NJ; j++) bfr[j] = ld8(&B_[(wn + j * 16 + l16) * 32 + cslot]);
#pragma unroll
        for (int i = 0; i < MI; i++)
#pragma unroll
            for (int j = 0; j < NJ; j++)
                acc[i][j] = __builtin_amdgcn_mfma_f32_16x16x32_bf16(af[i], bfr[j], acc[i][j], 0, 0, 0);
    }

    const int nbase = n0 + wn;
    float bj[NJ];
#pragma unroll
    for (int j = 0; j < NJ; j++) bj[j] = bias[nbase + j * 16 + l16];

    if constexpr (MODE == 1) {
#pragma unroll
        for (int j = 0; j < NJ; j++) {
#pragma unroll
            for (int i = 0; i < MI; i++)
#pragma unroll
                for (int r = 0; r < 4; r++) {
                    int m = m0 + wm + i * 16 + quad * 4 + r;
                    out[(size_t)m * CDIM + nbase + j * 16 + l16] = acc[i][j][r] + bj[j];
                }
        }
    } else {
        // ---- qkv epilogue; Ts overlays the staging buffers (loop is done) ----
        __syncthreads();                 // all waves done with As/Bs ds_reads
        uint16_t* T = smem + w * 64 * 68;
        const int gmb = m0 + wm;         // 64-aligned block of m (= ns) rows
        const int b = gmb >> 11, ns0 = gmb & 2047;
        const int lrow = lane >> 3, lch = lane & 7;   // store remap: 8 rows x 8 chunks

        if (nbase < 2048) {
            // q/k wave: T[m][n] m-major (stride 68); q gets QSCALE folded in
            const int which = nbase >> 10, h = (nbase & 1023) >> 6;
            const float sc = (which == 0) ? QSCALE : 1.0f;
#pragma unroll
            for (int i = 0; i < 4; i++)
#pragma unroll
                for (int j = 0; j < 4; j++)
#pragma unroll
                    for (int r = 0; r < 4; r++)
                        T[(i * 16 + quad * 4 + r) * 68 + j * 16 + l16] =
                            f32_bf16((acc[i][j][r] + bj[j]) * sc);
            LDS_FENCE();
            uint16_t* dst = ((which == 0) ? qw : kw) +
                            (((size_t)b * NH + h) * SEQ + ns0) * HD;
            // coalesced: per g, lanes cover rows g*8..g*8+7 fully (8x128B contig)
#pragma unroll
            for (int g = 0; g < 8; g++) {
                int r = g * 8 + lrow;
                bf16x8 v = ld8(&T[r * 68 + lch * 8]);
                *(bf16x8*)(dst + (size_t)r * HD + lch * 8) = v;
            }
        } else {
            // v wave: T[n(dd)][m(ns)] n-major; PLAIN [B,H,d,N] coalesced stores
#pragma unroll
            for (int i = 0; i < 4; i++)
#pragma unroll
                for (int j = 0; j < 4; j++) {
                    u32x2 pr;
                    pr.x = pack_bf16(acc[i][j][0] + bj[j], acc[i][j][1] + bj[j]);
                    pr.y = pack_bf16(acc[i][j][2] + bj[j], acc[i][j][3] + bj[j]);
                    *(u32x2*)&T[(j * 16 + l16) * 68 + i * 16 + quad * 4] = pr;
                }
            LDS_FENCE();
            const int h = (nbase - 2048) >> 6;
            uint16_t* dstb = vt + ((size_t)b * NH + h) * HD * SEQ + ns0;
            // per g: d-rows g*8..g*8+7, each 64 kv elems (128B) fully covered
#pragma unroll
            for (int g = 0; g < 8; g++) {
                int dr = g * 8 + lrow;
                bf16x8 v2 = ld8(&T[dr * 68 + lch * 8]);
                *(bf16x8*)(dstb + (size_t)dr * SEQ + lch * 8) = v2;
            }
        }
    }
}

// ---------------- flash attention: KV-tile 128, 32 q-rows per wave, 32x32 MFMA ----
// R5 schedule: R2 structure + per-wave kvb ROTATION for LDS-only cross-tile pipe.
//   Wave w processes kvb = (w+ph)&3. Its LAST phase needs next-tile kvb==w rows
//   32w..32w+31 — exactly the rows wave w itself DMA-staged (segs 4w..4w+3).
//   Own-DMA LDS writes become visible to own ds_reads after s_waitcnt vmcnt(4)
//   (drains the 4 K-DMAs; the 4 V-DMAs, issued after, stay in flight) — no
//   barrier, no global re-read, no vmcnt(0) queue drain (the R3/R4 mistake:
//   reg-global prefetch shared vmcnt with the DMA queue and forced full drains).
//   Every post-barrier phase thus starts with its S already computed.
//   setprio dropped (R4 evidence + m190: hurts barrier-locked lockstep blocks).
// Layouts (verified R1/R2): S^T = mfma_32x32x16(K-frag, Q-frag); C: col=q=lane&31,
// row=kv=(reg&3)+8*(reg>>2)+4*(lane>>5). p=exp2(S) -> cvt_pk pairs; 2x
// permlane32_swap build each 16-kv B-frag; PV = mfma(V-frag, P-frag); l on VALU
// add tree (+1 epilogue permlane swap). l/O sums are kvb-order-invariant.
__global__ __launch_bounds__(256) void attn_kernel(
        const uint16_t* __restrict__ qg, const uint16_t* __restrict__ kg,
        const uint16_t* __restrict__ vt, uint16_t* __restrict__ og) {
    __shared__ uint16_t Ks[2][128 * 64];  // [kv][d], 8x16B chunks/row, chunk ^= kv&7
    __shared__ uint16_t Vs[2][64 * 128];  // [d][kv], 16x16B chunks/row, chunk ^= d&15

    const int bh = blockIdx.x;         // 0..31  — XCD-affine (linear id % 8 = bh % 8)
    const int qt = blockIdx.y;         // 0..15
    const int tid = threadIdx.x;
    const int w = tid >> 6, lane = tid & 63;
    const int l32 = lane & 31, hi = lane >> 5;
    const int qrow0 = qt * 128 + w * 32;
    const size_t base = (size_t)bh * SEQ * HD;

    // Q B-frags: col = q = l32, k = d = s*16 + hi*8 + idx (held all kernel)
    bf16x8 qf[4];
#pragma unroll
    for (int s = 0; s < 4; s++)
        qf[s] = ld8(qg + base + (size_t)(qrow0 + l32) * HD + s * 16 + hi * 8);

    // K staging: 16 segs of 8 kv-rows (1KB); wave w stages segs 4w..4w+3
    //   (= kv rows 32w..32w+31 — wave w's own last-phase kvb block).
    const int krow = lane >> 3;
    const int kch = (lane & 7) ^ krow;
    // V staging: 16 segs of 4 d-rows x 128 kv (1KB); wave w stages segs 4w..4w+3.
    const int vrow = lane >> 4;
    const uint16_t* ksrc[4];
    const uint16_t* vsrc[4];
#pragma unroll
    for (int s = 0; s < 4; s++) {
        int seg = w * 4 + s;
        ksrc[s] = kg + base + (size_t)(seg * 8 + krow) * HD + kch * 8;
        int vd = seg * 4 + vrow;                       // d row
        int vch = (lane & 15) ^ (vd & 15);             // source chunk (4-bit xor)
        vsrc[s] = vt + base + (size_t)vd * SEQ + vch * 8;
    }

    f32x16 o_acc[2] = {};   // [mf]: d = mf*32 + (reg&3)+8*(reg>>2)+4*hi, col q=l32
    float l_red = 0.0f;     // per-lane partial: sum_kv(this lane's 16 kv rows) p

    auto stage = [&](int buf) {
        // K first (the 4 oldest DMAs — WAIT_K_DMA counts on this order)
#pragma unroll
        for (int s = 0; s < 4; s++) {
            int seg = w * 4 + s;
            gld16(ksrc[s], &Ks[buf][seg * 512]);
            ksrc[s] += 128 * HD;
        }
#pragma unroll
        for (int s = 0; s < 4; s++) {
            int seg = w * 4 + s;
            gld16(vsrc[s], &Vs[buf][seg * 512]);
            vsrc[s] += 128;
        }
    };

    // prologue: stage tile 0 into buffer 0
    stage(0);

    // hoisted read offsets (constant across tiles); row&7 == l32&7 for all kvb
    const int kxe = l32 & 7;    // K read xor: (row&7), row = kvb*32+l32
    const int vxe = l32 & 15;   // V read xor: (row&15), row = mf*32+l32
    const int krowb = l32 * 64;
    const int vrowb = l32 * 128;
    int kco[4];
#pragma unroll
    for (int s = 0; s < 4; s++) kco[s] = ((2 * s + hi) ^ kxe) * 8;
    int vco[4][2];
#pragma unroll
    for (int kvb = 0; kvb < 4; kvb++)
#pragma unroll
        for (int cp = 0; cp < 2; cp++)
            vco[kvb][cp] = ((kvb * 4 + cp * 2 + hi) ^ vxe) * 8;

    const f32x16 fzero = {};
    const int wbase = w * 2048;          // wave's own kvb block: rows 32w..32w+31

    // initial S for tile 0, kvb0 = w: own-staged K rows, visible after K-DMA drain
    f32x16 S[2];
    WAIT_K_DMA();
    {
        bf16x8 k0[4];
#pragma unroll
        for (int s = 0; s < 4; s++) k0[s] = ld8(&Ks[0][wbase] + krowb + kco[s]);
        S[0] = fzero;
#pragma unroll
        for (int s = 0; s < 4; s++)
            S[0] = __builtin_amdgcn_mfma_f32_32x32x16_bf16(k0[s], qf[s], S[0], 0, 0, 0);
    }

    const int NT = SEQ / 128;            // 16 tiles
    for (int it = 0; it < NT; ++it) {
        __syncthreads();   // tile-it K/V resident; prev buffer free for overwrite
        if (it + 1 < NT) stage((it + 1) & 1);
        const uint16_t* K_ = Ks[it & 1];
        const uint16_t* V_ = Vs[it & 1];

#pragma unroll
        for (int ph = 0; ph < 4; ph++) {
            const int cur = ph & 1, nxt = cur ^ 1;
            const int kvb = (w + ph) & 3;
            const bool have_next = (ph < 3) || (it + 1 < NT);

            // 1) K-frag reads feeding the next S (land under the softmax VALU)
            bf16x8 kf[4];
            if (ph < 3) {
                const int kvbn = (w + ph + 1) & 3;
#pragma unroll
                for (int s = 0; s < 4; s++)
                    kf[s] = ld8(K_ + kvbn * 2048 + krowb + kco[s]);
            } else if (it + 1 < NT) {
                // next tile, kvb == w: own freshly-DMA'd rows; drain own K-DMAs
                WAIT_K_DMA();
#pragma unroll
                for (int s = 0; s < 4; s++)
                    kf[s] = ld8(&Ks[(it + 1) & 1][wbase] + krowb + kco[s]);
            }

            // 2) this-kvb V-frag reads (consumed at phase end)
            bf16x8 vf[2][2];
#pragma unroll
            for (int cp = 0; cp < 2; cp++)
#pragma unroll
                for (int mf = 0; mf < 2; mf++)
                    vf[cp][mf] = ld8(V_ + vrowb + mf * 4096 + vco[kvb][cp]);

            // 3) softmax numerators p = exp2(S[cur]); l on the VALU add tree
            float p[16];
#pragma unroll
            for (int i = 0; i < 16; i++) p[i] = __builtin_amdgcn_exp2f(S[cur][i]);
            {
                float s0 = (p[0] + p[1]) + (p[2] + p[3]);
                float s1 = (p[4] + p[5]) + (p[6] + p[7]);
                float s2 = (p[8] + p[9]) + (p[10] + p[11]);
                float s3 = (p[12] + p[13]) + (p[14] + p[15]);
                l_red += (s0 + s1) + (s2 + s3);
            }
            uint32_t pk0[4], pk1[4];
#pragma unroll
            for (int c = 0; c < 4; c++) {
                pk0[c] = pack_bf16(p[4 * c + 0], p[4 * c + 1]);
                pk1[c] = pack_bf16(p[4 * c + 2], p[4 * c + 3]);
            }

            // 4) next-S QK MFMAs — overlap the pack/swap VALU chain
            if (have_next) {
                S[nxt] = fzero;
#pragma unroll
                for (int s = 0; s < 4; s++)
                    S[nxt] = __builtin_amdgcn_mfma_f32_32x32x16_bf16(kf[s], qf[s], S[nxt], 0, 0, 0);
            }

            // 5) PV for kvb
#pragma unroll
            for (int cp = 0; cp < 2; cp++) {
                uint32_t b0 = pk0[2 * cp], b2 = pk0[2 * cp + 1];
                uint32_t b1 = pk1[2 * cp], b3 = pk1[2 * cp + 1];
                swap32(b0, b2);   // -> word#0 (k idx 0,1), word#2 (k idx 4,5)
                swap32(b1, b3);   // -> word#1 (k idx 2,3), word#3 (k idx 6,7)
                u32x4 t;
                t.x = b0; t.y = b1; t.z = b2; t.w = b3;
                bf16x8 pb = __builtin_bit_cast(bf16x8, t);
#pragma unroll
                for (int mf = 0; mf < 2; mf++)
                    o_acc[mf] = __builtin_amdgcn_mfma_f32_32x32x16_bf16(vf[cp][mf], pb, o_acc[mf], 0, 0, 0);
            }
        }
    }

    // ---- epilogue: cross-half l reduction (1 permlane swap + add), O write ----
    uint32_t la = __builtin_bit_cast(uint32_t, l_red), lb = la;
    swap32(la, lb);
    const float l_tot = __builtin_bit_cast(float, la) + __builtin_bit_cast(float, lb);
    const float inv = __builtin_amdgcn_rcpf(l_tot);

    const int b = bh >> 4, h = bh & 15;
    const int ns = qrow0 + l32;
    uint16_t* orow = og + (((size_t)b * SEQ + ns) * NH + h) * HD;
#pragma unroll
    for (int mf = 0; mf < 2; mf++)
#pragma unroll
        for (int c = 0; c < 4; c++) {
            u32x2 pr;
            pr.x = pack_bf16(o_acc[mf][4 * c + 0] * inv, o_acc[mf][4 * c + 1] * inv);
            pr.y = pack_bf16(o_acc[mf][4 * c + 2] * inv, o_acc[mf][4 * c + 3] * inv);
            *(u32x2*)(orow + mf * 32 + c * 8 + hi * 4) = pr;
        }
}

extern "C" void kernel_launch(void* const* d_in, const int* in_sizes, int n_in,
                              void* d_out, int out_size, void* d_ws, size_t ws_size,
                              hipStream_t stream) {
    const float* x = (const float*)d_in[0];
    const float* Wqkv = (const float*)d_in[1];
    const float* bqkv = (const float*)d_in[2];
    const float* Wout = (const float*)d_in[3];
    const float* bout = (const float*)d_in[4];
    float* out = (float*)d_out;

    uint16_t* ws = (uint16_t*)d_ws;
    uint16_t* x_bf  = ws;                      // 4096*1024
    uint16_t* wqkvT = x_bf + 4194304;          // 3072*1024
    uint16_t* woutT = wqkvT + 3145728;         // 1024*1024
    uint16_t* qw    = woutT + 1048576;         // [B,H,N,d], pre-scaled by QSCALE
    uint16_t* kw    = qw + 4194304;            // [B,H,N,d]
    uint16_t* vtw   = kw + 4194304;            // [B,H,d,N] plain
    uint16_t* attn  = vtw + 4194304;           // [B,N,H,d]

    // cast x + transpose both weight matrices, one launch
    prep_kernel<<<8192, 256, 0, stream>>>(x, x_bf, Wqkv, wqkvT, Wout, woutT);

    // qkv = x @ Wqkv + b ; q (scaled) / k -> [B,H,N,d]; v -> [B,H,d,N] plain
    gemm_t<128, 128, 0><<<dim3(24, 32), 256, 0, stream>>>(
        x_bf, wqkvT, 1024, bqkv, qw, kw, vtw, nullptr);

    // flash attention -> attn [B,N,H,d] bf16   (grid.x = bh for XCD affinity)
    attn_kernel<<<dim3(32, 16), 256, 0, stream>>>(qw, kw, vtw, attn);

    // out = attn @ Wout + b_out (f32); 64x128 tiles -> 512 blocks (2/CU)
    gemm_t<64, 128, 1><<<dim3(8, 64), 256, 0, stream>>>(
        attn, woutT, 1024, bout, nullptr, nullptr, nullptr, out);
}